// Round 4
// baseline (219.455 us; speedup 1.0000x reference)
//
#include <hip/hip_runtime.h>

// Problem constants
#define NPTS 100000
#define NCH 32      // n
#define KNB 32      // K
#define MCL 16      // M

constexpr int IB1  = 128;   // i-blocks in encoder partial kernel
constexpr int SBLK = 256;   // blocks in S-partial kernel
constexpr int STILE = 64;   // points per LDS tile in S kernel

// Workspace layout (bytes) — 16B-aligned
constexpr size_t OFF_ENC_PART = 0;                     // 32*128 dbl = 32768
constexpr size_t OFF_ENC      = 32768;                 // 32 dbl     = 256
constexpr size_t OFF_INVW2    = OFF_ENC + 256;         // 512 f32    = 2048
constexpr size_t OFF_INVS     = OFF_INVW2 + 2048;      // 1024 f32   = 4096
constexpr size_t OFF_SACC     = OFF_INVS + 4096;       // 1024 dbl   = 8192
constexpr size_t OFF_GT       = OFF_SACC + 8192;       // N*32 f32   = 12800000

// ---------------------------------------------------------------------------
// Kernel 1: encoder matvec partials. encoded[j] = sum_i enc_w[j,i]*x[i].
// Block 0 also zeroes Sacc (runs before k_spart in stream order).
__global__ __launch_bounds__(256) void k_enc_partial(
    const float* __restrict__ x, const float* __restrict__ enc_w,
    double* __restrict__ part, double* __restrict__ Sacc) {
  int tid = threadIdx.x;
  if (blockIdx.x == 0) {
    for (int q = tid; q < 1024; q += 256) Sacc[q] = 0.0;
  }
  int jg = blockIdx.x & 3;
  int ib = blockIdx.x >> 2;
  int j0 = jg * 8;
  double acc[8];
#pragma unroll
  for (int jj = 0; jj < 8; ++jj) acc[jj] = 0.0;
  for (int i = ib * 256 + tid; i < NPTS; i += IB1 * 256) {
    float xv = x[i];
#pragma unroll
    for (int jj = 0; jj < 8; ++jj)
      acc[jj] += (double)enc_w[(size_t)(j0 + jj) * NPTS + i] * (double)xv;
  }
#pragma unroll
  for (int jj = 0; jj < 8; ++jj) {
    double v = acc[jj];
#pragma unroll
    for (int off = 32; off >= 1; off >>= 1) v += __shfl_down(v, off);
    acc[jj] = v;
  }
  __shared__ double sw[4][8];
  int lane = tid & 63, w = tid >> 6;
  if (lane == 0)
    for (int jj = 0; jj < 8; ++jj) sw[w][jj] = acc[jj];
  __syncthreads();
  if (tid < 8) {
    double s = sw[0][tid] + sw[1][tid] + sw[2][tid] + sw[3][tid];
    part[(size_t)(j0 + tid) * IB1 + ib] = s;
  }
}

// ---------------------------------------------------------------------------
// Kernel 2 v2: parallel reduce of encoder partials (512 threads cooperative);
// bandwidths = bw_w@encoded + bw_b; invw2[m*32+j] = 1/w^2.
__global__ __launch_bounds__(512) void k_head(
    const double* __restrict__ part, const float* __restrict__ enc_b,
    const float* __restrict__ bw_w, const float* __restrict__ bw_b,
    double* __restrict__ enc_out, float* __restrict__ invw2) {
  __shared__ double es[32];
  __shared__ double sred[32][16];
  int tid = threadIdx.x;
  int j = tid >> 4, slot = tid & 15;
  double s = 0.0;
#pragma unroll
  for (int r = 0; r < 8; ++r) s += part[j * 128 + slot * 8 + r];
  sred[j][slot] = s;
  __syncthreads();
  if (tid < 32) {
    double t = 0.0;
    for (int q = 0; q < 16; ++q) t += sred[tid][q];
    t += (double)enc_b[tid];
    enc_out[tid] = t;
    es[tid] = t;
  }
  __syncthreads();
  double wd = 0.0;
  for (int c = 0; c < 32; ++c) wd += (double)bw_w[tid * 32 + c] * es[c];
  wd += (double)bw_b[tid];
  int jr = tid >> 4, m = tid & 15;
  invw2[m * 32 + jr] = (float)(1.0 / (wd * wd));
}

// ---------------------------------------------------------------------------
// Kernel 3: gT[i*32+j] = (float)enc[j] * decoder[j*N+i]
__global__ __launch_bounds__(256) void k_gt(
    const float* __restrict__ decoder, const double* __restrict__ enc,
    float* __restrict__ gT) {
  __shared__ float tile[32][33];
  __shared__ float ef[32];
  int tx = threadIdx.x & 31, ty = threadIdx.x >> 5;  // ty: 0..7
  if (threadIdx.x < 32) ef[threadIdx.x] = (float)enc[threadIdx.x];
  int i0 = blockIdx.x * 32;
  for (int jj = ty; jj < 32; jj += 8)
    tile[tx][jj] = decoder[(size_t)jj * NPTS + i0 + tx];
  __syncthreads();
  for (int ii = ty; ii < 32; ii += 8)
    gT[(size_t)(i0 + ii) * 32 + tx] = tile[ii][tx] * ef[tx];
}

// ---------------------------------------------------------------------------
// Kernel 4 v3: S[j,k] partials -> f64 atomicAdd into Sacc[j*32+k].
// 256 threads: thread = (j = tid>>3, kq = tid&7) owns k = kq*4..kq*4+3.
__global__ __launch_bounds__(256) void k_spart(
    const float* __restrict__ nd, const int* __restrict__ labels,
    const float* __restrict__ invw2, double* __restrict__ Sacc) {
  __shared__ float iw[512];
  __shared__ __align__(16) float d2t[STILE * 32];  // negated d^2, k-contiguous
  __shared__ float ict[STILE * 32];                // iw[lab[i]*32+j]
  int tid = threadIdx.x;
  for (int q = tid; q < 512; q += 256) iw[q] = invw2[q];
  int j = tid >> 3, kq = tid & 7;
  double a0 = 0.0, a1 = 0.0, a2 = 0.0, a3 = 0.0;
  const int ntiles = (NPTS + STILE - 1) / STILE;  // 1563
  for (int tile = blockIdx.x; tile < ntiles; tile += SBLK) {
    int i0 = tile * STILE;
    __syncthreads();  // prev readers done; also covers iw staging (iter 0)
#pragma unroll
    for (int q = tid; q < STILE * 32; q += 256) {
      int ii = q >> 5;
      int gi = i0 + ii;
      float v = (gi < NPTS) ? nd[(size_t)i0 * 32 + q] : 1.0e18f;
      d2t[q] = -v * v;  // -1e36 for invalid -> relu term = 0
      int lab = (gi < NPTS) ? labels[gi] : 0;
      ict[q] = iw[lab * 32 + (q & 31)];
    }
    __syncthreads();
    float t0 = 0.0f, t1 = 0.0f, t2 = 0.0f, t3 = 0.0f;
#pragma unroll 8
    for (int ii = 0; ii < STILE; ++ii) {
      float icv = ict[ii * 32 + j];
      float4 d2 = *(const float4*)&d2t[ii * 32 + kq * 4];
      t0 += fmaxf(fmaf(d2.x, icv, 1.0f), 0.0f);
      t1 += fmaxf(fmaf(d2.y, icv, 1.0f), 0.0f);
      t2 += fmaxf(fmaf(d2.z, icv, 1.0f), 0.0f);
      t3 += fmaxf(fmaf(d2.w, icv, 1.0f), 0.0f);
    }
    a0 += (double)t0; a1 += (double)t1; a2 += (double)t2; a3 += (double)t3;
  }
  double* dst = &Sacc[j * 32 + kq * 4];
  unsafeAtomicAdd(dst + 0, a0);
  unsafeAtomicAdd(dst + 1, a1);
  unsafeAtomicAdd(dst + 2, a2);
  unsafeAtomicAdd(dst + 3, a3);
}

// ---------------------------------------------------------------------------
// Kernel 5 v2: invert Sacc -> invS[k*32+j]. One block.
__global__ __launch_bounds__(1024) void k_sinv(
    const double* __restrict__ Sacc, float* __restrict__ invS) {
  int t = threadIdx.x;  // = j*32+k
  int j = t >> 5, k = t & 31;
  invS[k * 32 + j] = (float)(1.0 / Sacc[t]);
}

// ---------------------------------------------------------------------------
// Kernel 6 v4: one-shot, 4 points per wave, no LDS, no shfl on address path.
// lane l: q=l&7 -> j quad (j=q*4..+3), g=l>>3 -> k in {g,g+8,g+16,g+24}.
// All 16 dwordx4 gathers issued before any use.
__global__ __launch_bounds__(256, 3) void k_main(
    const float* __restrict__ nd, const int* __restrict__ nid,
    const int* __restrict__ labels, const float* __restrict__ gT,
    const float* __restrict__ invw2, const float* __restrict__ invS,
    float* __restrict__ out) {
  int tid = threadIdx.x;
  int lane = tid & 63;
  int w = tid >> 6;
  int q = lane & 7;
  int g = lane >> 3;
  int wv = blockIdx.x * 4 + w;  // 0..24999

  int id[4][4];
  float dvv[4][4];
  int lab[4];
#pragma unroll
  for (int p = 0; p < 4; ++p) {
    int i = wv + p * 25000;
    lab[p] = labels[i];
    int base = i * 32;
#pragma unroll
    for (int kk = 0; kk < 4; ++kk) {
      id[p][kk] = nid[base + kk * 8 + g];
      dvv[p][kk] = nd[base + kk * 8 + g];
    }
  }
  // issue all 16 gathers
  float4 gv[4][4];
#pragma unroll
  for (int p = 0; p < 4; ++p)
#pragma unroll
    for (int kk = 0; kk < 4; ++kk)
      gv[p][kk] = *(const float4*)&gT[(size_t)id[p][kk] * 32 + q * 4];
  float4 iwv[4];
#pragma unroll
  for (int p = 0; p < 4; ++p)
    iwv[p] = *(const float4*)&invw2[lab[p] * 32 + q * 4];
  float4 sv[4];
#pragma unroll
  for (int kk = 0; kk < 4; ++kk)
    sv[kk] = *(const float4*)&invS[(kk * 8 + g) * 32 + q * 4];

  double a[4] = {0.0, 0.0, 0.0, 0.0};
#pragma unroll
  for (int p = 0; p < 4; ++p) {
#pragma unroll
    for (int kk = 0; kk < 4; ++kk) {
      float md = -dvv[p][kk] * dvv[p][kk];
      float u0 = fmaxf(fmaf(md, iwv[p].x, 1.0f), 0.0f);
      float u1 = fmaxf(fmaf(md, iwv[p].y, 1.0f), 0.0f);
      float u2 = fmaxf(fmaf(md, iwv[p].z, 1.0f), 0.0f);
      float u3 = fmaxf(fmaf(md, iwv[p].w, 1.0f), 0.0f);
      a[p] += (double)(gv[p][kk].x * (u0 * sv[kk].x));
      a[p] += (double)(gv[p][kk].y * (u1 * sv[kk].y));
      a[p] += (double)(gv[p][kk].z * (u2 * sv[kk].z));
      a[p] += (double)(gv[p][kk].w * (u3 * sv[kk].w));
    }
  }
#pragma unroll
  for (int off = 32; off >= 1; off >>= 1) {
#pragma unroll
    for (int p = 0; p < 4; ++p) a[p] += __shfl_down(a[p], off);
  }
  if (lane == 0) {
#pragma unroll
    for (int p = 0; p < 4; ++p) out[wv + p * 25000] = (float)a[p];
  }
}

// ---------------------------------------------------------------------------
extern "C" void kernel_launch(void* const* d_in, const int* in_sizes, int n_in,
                              void* d_out, int out_size, void* d_ws,
                              size_t ws_size, hipStream_t stream) {
  const float* x       = (const float*)d_in[0];
  const float* enc_w   = (const float*)d_in[1];
  const float* enc_b   = (const float*)d_in[2];
  const float* decoder = (const float*)d_in[3];
  const float* bw_w    = (const float*)d_in[4];
  const float* bw_b    = (const float*)d_in[5];
  const float* nd      = (const float*)d_in[6];
  const int*   nid     = (const int*)d_in[7];
  const int*   labels  = (const int*)d_in[8];
  float* out = (float*)d_out;

  char* ws = (char*)d_ws;
  double* part  = (double*)(ws + OFF_ENC_PART);
  double* enc_d = (double*)(ws + OFF_ENC);
  float*  invw2 = (float*)(ws + OFF_INVW2);
  float*  invS  = (float*)(ws + OFF_INVS);
  double* Sacc  = (double*)(ws + OFF_SACC);
  float*  gT    = (float*)(ws + OFF_GT);

  hipLaunchKernelGGL(k_enc_partial, dim3(512), dim3(256), 0, stream, x, enc_w, part, Sacc);
  hipLaunchKernelGGL(k_head, dim3(1), dim3(512), 0, stream, part, enc_b, bw_w, bw_b, enc_d, invw2);
  hipLaunchKernelGGL(k_gt, dim3(3125), dim3(256), 0, stream, decoder, enc_d, gT);
  hipLaunchKernelGGL(k_spart, dim3(SBLK), dim3(256), 0, stream, nd, labels, invw2, Sacc);
  hipLaunchKernelGGL(k_sinv, dim3(1), dim3(1024), 0, stream, Sacc, invS);
  // 6250 blocks x 4 waves = 25000 waves; each wave: points {wv, +25k, +50k, +75k}
  hipLaunchKernelGGL(k_main, dim3(6250), dim3(256), 0, stream, nd, nid, labels, gT, invw2, invS, out);
}

// Round 5
// 199.084 us; speedup vs baseline: 1.1023x; 1.1023x over previous
//
#include <hip/hip_runtime.h>

// Problem constants
#define NPTS 100000
#define NCH 32      // n
#define KNB 32      // K
#define MCL 16      // M

constexpr int IB1  = 128;   // i-blocks in encoder partial kernel
constexpr int SBLK = 512;   // blocks in S-partial kernel

// Workspace layout (bytes). spart reuses [0, 4MB): enc partials (32KB) live
// only from k_enc to k_head; k_spart writes spart there afterwards.
constexpr size_t OFF_SPART    = 0;                     // 512*1024 dbl = 4194304 (also enc part 32768 early)
constexpr size_t OFF_ENC      = 4194304;               // 32 dbl   = 256
constexpr size_t OFF_INVW2    = OFF_ENC + 256;         // 512 f32  = 2048
constexpr size_t OFF_INVS     = OFF_INVW2 + 2048;      // 1024 f32 = 4096
constexpr size_t OFF_SACC     = OFF_INVS + 4096;       // 1024 dbl = 8192
constexpr size_t OFF_GT       = OFF_SACC + 8192;       // N*32 f32 = 12800000
// total ~17.0 MB (<= R3's proven footprint)

// ---------------------------------------------------------------------------
// Kernel 1: encoder matvec partials. encoded[j] = sum_i enc_w[j,i]*x[i].
// Block 0 also zeroes Sacc (runs before k_sred2 in stream order).
__global__ __launch_bounds__(256) void k_enc_partial(
    const float* __restrict__ x, const float* __restrict__ enc_w,
    double* __restrict__ part, double* __restrict__ Sacc) {
  int tid = threadIdx.x;
  if (blockIdx.x == 0) {
    for (int q = tid; q < 1024; q += 256) Sacc[q] = 0.0;
  }
  int jg = blockIdx.x & 3;
  int ib = blockIdx.x >> 2;
  int j0 = jg * 8;
  double acc[8];
#pragma unroll
  for (int jj = 0; jj < 8; ++jj) acc[jj] = 0.0;
  for (int i = ib * 256 + tid; i < NPTS; i += IB1 * 256) {
    float xv = x[i];
#pragma unroll
    for (int jj = 0; jj < 8; ++jj)
      acc[jj] += (double)enc_w[(size_t)(j0 + jj) * NPTS + i] * (double)xv;
  }
#pragma unroll
  for (int jj = 0; jj < 8; ++jj) {
    double v = acc[jj];
#pragma unroll
    for (int off = 32; off >= 1; off >>= 1) v += __shfl_down(v, off);
    acc[jj] = v;
  }
  __shared__ double sw[4][8];
  int lane = tid & 63, w = tid >> 6;
  if (lane == 0)
    for (int jj = 0; jj < 8; ++jj) sw[w][jj] = acc[jj];
  __syncthreads();
  if (tid < 8) {
    double s = sw[0][tid] + sw[1][tid] + sw[2][tid] + sw[3][tid];
    part[(size_t)(j0 + tid) * IB1 + ib] = s;
  }
}

// ---------------------------------------------------------------------------
// Kernel 2: parallel reduce of encoder partials; bandwidths = bw_w@enc + bw_b;
// invw2[m*32+j] = 1/w^2.
__global__ __launch_bounds__(512) void k_head(
    const double* __restrict__ part, const float* __restrict__ enc_b,
    const float* __restrict__ bw_w, const float* __restrict__ bw_b,
    double* __restrict__ enc_out, float* __restrict__ invw2) {
  __shared__ double es[32];
  __shared__ double sred[32][16];
  int tid = threadIdx.x;
  int j = tid >> 4, slot = tid & 15;
  double s = 0.0;
#pragma unroll
  for (int r = 0; r < 8; ++r) s += part[j * 128 + slot * 8 + r];
  sred[j][slot] = s;
  __syncthreads();
  if (tid < 32) {
    double t = 0.0;
    for (int q = 0; q < 16; ++q) t += sred[tid][q];
    t += (double)enc_b[tid];
    enc_out[tid] = t;
    es[tid] = t;
  }
  __syncthreads();
  double wd = 0.0;
  for (int c = 0; c < 32; ++c) wd += (double)bw_w[tid * 32 + c] * es[c];
  wd += (double)bw_b[tid];
  int jr = tid >> 4, m = tid & 15;
  invw2[m * 32 + jr] = (float)(1.0 / (wd * wd));
}

// ---------------------------------------------------------------------------
// Kernel 3: gT[i*32+j] = (float)enc[j] * decoder[j*N+i]
__global__ __launch_bounds__(256) void k_gt(
    const float* __restrict__ decoder, const double* __restrict__ enc,
    float* __restrict__ gT) {
  __shared__ float tile[32][33];
  __shared__ float ef[32];
  int tx = threadIdx.x & 31, ty = threadIdx.x >> 5;  // ty: 0..7
  if (threadIdx.x < 32) ef[threadIdx.x] = (float)enc[threadIdx.x];
  int i0 = blockIdx.x * 32;
  for (int jj = ty; jj < 32; jj += 8)
    tile[tx][jj] = decoder[(size_t)jj * NPTS + i0 + tx];
  __syncthreads();
  for (int ii = ty; ii < 32; ii += 8)
    gT[(size_t)(i0 + ii) * 32 + tx] = tile[ii][tx] * ef[tx];
}

// ---------------------------------------------------------------------------
// Kernel 4 v4: S partials, no LDS, no barriers. thread = (j=tid>>3, kq=tid&7)
// owns k = kq*4..+3. Per point per wave: labels dword (uniform), invw2 dword
// (L1-hot), nd dwordx4 (one broadcast 128B line). f32 accum folded to f64
// every 16 points. Strided i-loop -> natural bounds, blocks independent.
__global__ __launch_bounds__(256) void k_spart(
    const float* __restrict__ nd, const int* __restrict__ labels,
    const float* __restrict__ invw2, double* __restrict__ spart) {
  int tid = threadIdx.x;
  int j = tid >> 3, kq = tid & 7;
  double a0 = 0.0, a1 = 0.0, a2 = 0.0, a3 = 0.0;
  int i = blockIdx.x;
  while (i < NPTS) {
    float t0 = 0.0f, t1 = 0.0f, t2 = 0.0f, t3 = 0.0f;
#pragma unroll 4
    for (int c = 0; c < 16 && i < NPTS; ++c, i += SBLK) {
      int lab = labels[i];
      float icv = invw2[lab * 32 + j];
      float4 d = *(const float4*)&nd[(size_t)i * 32 + kq * 4];
      t0 += fmaxf(fmaf(-(d.x * d.x), icv, 1.0f), 0.0f);
      t1 += fmaxf(fmaf(-(d.y * d.y), icv, 1.0f), 0.0f);
      t2 += fmaxf(fmaf(-(d.z * d.z), icv, 1.0f), 0.0f);
      t3 += fmaxf(fmaf(-(d.w * d.w), icv, 1.0f), 0.0f);
    }
    a0 += (double)t0; a1 += (double)t1; a2 += (double)t2; a3 += (double)t3;
  }
  size_t base = (size_t)blockIdx.x * 1024 + j * 32 + kq * 4;
  spart[base + 0] = a0;
  spart[base + 1] = a1;
  spart[base + 2] = a2;
  spart[base + 3] = a3;
}

// ---------------------------------------------------------------------------
// Kernel 5a: reduce spart rows -> Sacc via f64 atomics (depth 16/address).
// 64 blocks x 256: gt = (jk, seg); each thread sums 32 rows, coalesced.
__global__ __launch_bounds__(256) void k_sred2(
    const double* __restrict__ spart, double* __restrict__ Sacc) {
  int gt = blockIdx.x * 256 + threadIdx.x;  // 0..16383
  int jk = gt & 1023;
  int seg = gt >> 10;  // 0..15
  double s = 0.0;
#pragma unroll 8
  for (int r = 0; r < 32; ++r)
    s += spart[(size_t)(seg * 32 + r) * 1024 + jk];
  unsafeAtomicAdd(&Sacc[jk], s);
}

// ---------------------------------------------------------------------------
// Kernel 5b: invert Sacc -> invS[k*32+j]. One block.
__global__ __launch_bounds__(1024) void k_sinv(
    const double* __restrict__ Sacc, float* __restrict__ invS) {
  int t = threadIdx.x;  // = j*32+k
  int j = t >> 5, k = t & 31;
  invS[k * 32 + j] = (float)(1.0 / Sacc[t]);
}

// ---------------------------------------------------------------------------
// Kernel 6 v4: one-shot, 4 points per wave, no LDS, no shfl on address path.
// lane l: q=l&7 -> j quad (j=q*4..+3), g=l>>3 -> k in {g,g+8,g+16,g+24}.
// All 16 dwordx4 gathers issued before any use.
__global__ __launch_bounds__(256, 3) void k_main(
    const float* __restrict__ nd, const int* __restrict__ nid,
    const int* __restrict__ labels, const float* __restrict__ gT,
    const float* __restrict__ invw2, const float* __restrict__ invS,
    float* __restrict__ out) {
  int tid = threadIdx.x;
  int lane = tid & 63;
  int w = tid >> 6;
  int q = lane & 7;
  int g = lane >> 3;
  int wv = blockIdx.x * 4 + w;  // 0..24999

  int id[4][4];
  float dvv[4][4];
  int lab[4];
#pragma unroll
  for (int p = 0; p < 4; ++p) {
    int i = wv + p * 25000;
    lab[p] = labels[i];
    int base = i * 32;
#pragma unroll
    for (int kk = 0; kk < 4; ++kk) {
      id[p][kk] = nid[base + kk * 8 + g];
      dvv[p][kk] = nd[base + kk * 8 + g];
    }
  }
  float4 gv[4][4];
#pragma unroll
  for (int p = 0; p < 4; ++p)
#pragma unroll
    for (int kk = 0; kk < 4; ++kk)
      gv[p][kk] = *(const float4*)&gT[(size_t)id[p][kk] * 32 + q * 4];
  float4 iwv[4];
#pragma unroll
  for (int p = 0; p < 4; ++p)
    iwv[p] = *(const float4*)&invw2[lab[p] * 32 + q * 4];
  float4 sv[4];
#pragma unroll
  for (int kk = 0; kk < 4; ++kk)
    sv[kk] = *(const float4*)&invS[(kk * 8 + g) * 32 + q * 4];

  double a[4] = {0.0, 0.0, 0.0, 0.0};
#pragma unroll
  for (int p = 0; p < 4; ++p) {
#pragma unroll
    for (int kk = 0; kk < 4; ++kk) {
      float md = -dvv[p][kk] * dvv[p][kk];
      float u0 = fmaxf(fmaf(md, iwv[p].x, 1.0f), 0.0f);
      float u1 = fmaxf(fmaf(md, iwv[p].y, 1.0f), 0.0f);
      float u2 = fmaxf(fmaf(md, iwv[p].z, 1.0f), 0.0f);
      float u3 = fmaxf(fmaf(md, iwv[p].w, 1.0f), 0.0f);
      a[p] += (double)(gv[p][kk].x * (u0 * sv[kk].x));
      a[p] += (double)(gv[p][kk].y * (u1 * sv[kk].y));
      a[p] += (double)(gv[p][kk].z * (u2 * sv[kk].z));
      a[p] += (double)(gv[p][kk].w * (u3 * sv[kk].w));
    }
  }
#pragma unroll
  for (int off = 32; off >= 1; off >>= 1) {
#pragma unroll
    for (int p = 0; p < 4; ++p) a[p] += __shfl_down(a[p], off);
  }
  if (lane == 0) {
#pragma unroll
    for (int p = 0; p < 4; ++p) out[wv + p * 25000] = (float)a[p];
  }
}

// ---------------------------------------------------------------------------
extern "C" void kernel_launch(void* const* d_in, const int* in_sizes, int n_in,
                              void* d_out, int out_size, void* d_ws,
                              size_t ws_size, hipStream_t stream) {
  const float* x       = (const float*)d_in[0];
  const float* enc_w   = (const float*)d_in[1];
  const float* enc_b   = (const float*)d_in[2];
  const float* decoder = (const float*)d_in[3];
  const float* bw_w    = (const float*)d_in[4];
  const float* bw_b    = (const float*)d_in[5];
  const float* nd      = (const float*)d_in[6];
  const int*   nid     = (const int*)d_in[7];
  const int*   labels  = (const int*)d_in[8];
  float* out = (float*)d_out;

  char* ws = (char*)d_ws;
  double* spart = (double*)(ws + OFF_SPART);
  double* part  = (double*)(ws + OFF_SPART);  // overlap: dead before k_spart
  double* enc_d = (double*)(ws + OFF_ENC);
  float*  invw2 = (float*)(ws + OFF_INVW2);
  float*  invS  = (float*)(ws + OFF_INVS);
  double* Sacc  = (double*)(ws + OFF_SACC);
  float*  gT    = (float*)(ws + OFF_GT);

  hipLaunchKernelGGL(k_enc_partial, dim3(512), dim3(256), 0, stream, x, enc_w, part, Sacc);
  hipLaunchKernelGGL(k_head, dim3(1), dim3(512), 0, stream, part, enc_b, bw_w, bw_b, enc_d, invw2);
  hipLaunchKernelGGL(k_gt, dim3(3125), dim3(256), 0, stream, decoder, enc_d, gT);
  hipLaunchKernelGGL(k_spart, dim3(SBLK), dim3(256), 0, stream, nd, labels, invw2, spart);
  hipLaunchKernelGGL(k_sred2, dim3(64), dim3(256), 0, stream, spart, Sacc);
  hipLaunchKernelGGL(k_sinv, dim3(1), dim3(1024), 0, stream, Sacc, invS);
  hipLaunchKernelGGL(k_main, dim3(6250), dim3(256), 0, stream, nd, nid, labels, gT, invw2, invS, out);
}